// Round 5
// baseline (558.733 us; speedup 1.0000x reference)
//
#include <hip/hip_runtime.h>
#include <stdint.h>

// SparseAutoEncoder: hypernetwork-generated per-sample MLP weights, fused.
// EN layers (rows in en_W2): (2000,200) lin @0, (200,100) tanh @400200, (100,10) lin @420300
// DE layers (rows in de_W2): (10,100) lin @0, (100,200) tanh @1100, (200,2000) lin @21300
// All hyper widths K = 64, batch B = 64. h layout: (b,k) b-major. xT layouts: (i,b) i-major.

// ---------------------------------------------------------------------------
// prep: transpose z (64x2000) -> zT (2000x64), and compute h_en, h_de (64x64)
// ---------------------------------------------------------------------------
__global__ __launch_bounds__(256) void prep_kernel(
    const float* __restrict__ z, const float* __restrict__ mu,
    const float* __restrict__ enW0, const float* __restrict__ enb0,
    const float* __restrict__ enW1, const float* __restrict__ enb1,
    const float* __restrict__ deW0, const float* __restrict__ deb0,
    const float* __restrict__ deW1, const float* __restrict__ deb1,
    float* __restrict__ zT, float* __restrict__ hen, float* __restrict__ hde)
{
    __shared__ float tile[64 * 65];
    __shared__ float h0s[4][64];
    const int bid  = blockIdx.x;
    const int lane = threadIdx.x & 63;
    const int g    = threadIdx.x >> 6;

    if (bid < 32) {
        // 64x64 tile transpose of z
        const int t0 = bid * 64;
        for (int bb = g; bb < 64; bb += 4) {
            int i = t0 + lane;
            tile[bb * 65 + lane] = (i < 2000) ? z[bb * 2000 + i] : 0.f;
        }
        __syncthreads();
        for (int ii = g; ii < 64; ii += 4) {
            int i = t0 + ii;
            if (i < 2000) zT[i * 64 + lane] = tile[lane * 65 + ii];
        }
    } else {
        // hypernetwork MLP: task = (which, b); lane = output neuron j
        const int task  = (bid - 32) * 4 + g;   // 0..127
        const int which = task >> 6;            // 0 = en, 1 = de
        const int b     = task & 63;
        const float* W0 = which ? deW0 : enW0;
        const float* b0 = which ? deb0 : enb0;
        const float* W1 = which ? deW1 : enW1;
        const float* b1 = which ? deb1 : enb1;
        float* hout     = which ? hde : hen;
        const int j = lane;
        float m0 = mu[b * 4 + 0], m1 = mu[b * 4 + 1], m2 = mu[b * 4 + 2], m3 = mu[b * 4 + 3];
        float v = tanhf(m0 * W0[j * 4 + 0] + m1 * W0[j * 4 + 1] +
                        m2 * W0[j * 4 + 2] + m3 * W0[j * 4 + 3] + b0[j]);
        h0s[g][j] = v;
        __syncthreads();
        float a = b1[j];
        const float* W1r = W1 + j * 64;
        #pragma unroll 8
        for (int k = 0; k < 64; ++k) a = fmaf(h0s[g][k], W1r[k], a);
        hout[b * 64 + j] = tanhf(a);
    }
}

// ---------------------------------------------------------------------------
// async global -> LDS, 4 bytes per lane (size literal required by builtin).
// Global src is per-lane; LDS dest is wave-uniform base + lane*4 (linear).
// ---------------------------------------------------------------------------
__device__ __forceinline__ void gload4(const float* g, float* l)
{
    __builtin_amdgcn_global_load_lds(
        (const __attribute__((address_space(1))) void*)g,
        (__attribute__((address_space(3))) void*)l,
        4, 0, 0);
}

// ---------------------------------------------------------------------------
// fused hyper-FC layer, 4x4 outer-product microkernel fed by a 3-buffer
// global_load_lds ring with COUNTED vmcnt (T3+T4): tile t+2 staged during
// tile t, so each staged tile has ~2x640cy of compute to cover ~900cy HBM
// latency. Per wave per tile: exactly 10 staging loads (5 W + 5 X chunks of
// 256B) -> uniform `s_waitcnt vmcnt(10)` + raw s_barrier per tile; last tile
// peeled with vmcnt(0). In-order vmcnt retirement (m135) makes the oldest
// (= tile t's) loads the ones waited on.
//   y[b,o] = act( sum_k h[b,k]*(T[b,k] + Wbias[o,k]) + sum_i x[b,i]*b2[o*NI+i]
//                 + b2[NO*NI+o] ),     T[b,k] = sum_i xT[i,b] * W2[(o*NI+i),k]
// Lane layout: kg = lane&15 -> k-quad 4*kg..+3 ; bgl = lane>>4 ;
//              wave owns b-rows [wave*16, +16); lane's b-quad = wave*16+bgl*4.
// Per row: 2 ds_read_b128 + 16 FMAs. No scalar-memory, no VMEM in hot loop.
// NOTE: TANH layers must NOT be atomic-split (tanh of partial sums is wrong).
// ---------------------------------------------------------------------------
template <int NI, int NO, int NSPLIT, bool TANH, bool ATOMIC>
__global__ __launch_bounds__(256, 8) void fc_kernel(
    const float* __restrict__ xT,   // NI x 64
    const float* __restrict__ h,    // 64 x 64 (b-major)
    const float* __restrict__ W2,   // layer base, (NO*NI+NO) x 64
    const float* __restrict__ b2,   // layer base, NO*NI+NO
    float* __restrict__ yT)         // NO x 64
{
    const int lane = threadIdx.x & 63;
    const int wave = threadIdx.x >> 6;
    const int kg   = lane & 15;          // k = 4*kg .. 4*kg+3
    const int bgl  = lane >> 4;          // 0..3
    const int b0   = wave * 16 + bgl * 4;

    const int o = blockIdx.x % NO;       // consecutive blocks share s -> share x chunk in L2
    const int s = blockIdx.x / NO;
    constexpr int CH = NI / NSPLIT;      // NI divisible by NSPLIT
    const int i0   = s * CH;
    const int iend = i0 + CH;

    constexpr int  TR     = 20;                          // rows per tile (5 KB per array)
    constexpr bool STAGED = (CH >= 2 * TR) && (CH % TR == 0);
    constexpr int  NT     = STAGED ? (CH / TR) : 1;

    __shared__ float Wl[STAGED ? 3 * TR * 64 : 4];
    __shared__ float Xl[STAGED ? 3 * TR * 64 : 4];

    float acc[4][4];
    #pragma unroll
    for (int a = 0; a < 4; ++a)
        #pragma unroll
        for (int c = 0; c < 4; ++c) acc[a][c] = 0.f;

    auto fma16 = [&](const float4& w, const float4& x) {
        acc[0][0] = fmaf(x.x, w.x, acc[0][0]);
        acc[0][1] = fmaf(x.x, w.y, acc[0][1]);
        acc[0][2] = fmaf(x.x, w.z, acc[0][2]);
        acc[0][3] = fmaf(x.x, w.w, acc[0][3]);
        acc[1][0] = fmaf(x.y, w.x, acc[1][0]);
        acc[1][1] = fmaf(x.y, w.y, acc[1][1]);
        acc[1][2] = fmaf(x.y, w.z, acc[1][2]);
        acc[1][3] = fmaf(x.y, w.w, acc[1][3]);
        acc[2][0] = fmaf(x.z, w.x, acc[2][0]);
        acc[2][1] = fmaf(x.z, w.y, acc[2][1]);
        acc[2][2] = fmaf(x.z, w.z, acc[2][2]);
        acc[2][3] = fmaf(x.z, w.w, acc[2][3]);
        acc[3][0] = fmaf(x.w, w.x, acc[3][0]);
        acc[3][1] = fmaf(x.w, w.y, acc[3][1]);
        acc[3][2] = fmaf(x.w, w.z, acc[3][2]);
        acc[3][3] = fmaf(x.w, w.w, acc[3][3]);
    };

    if constexpr (STAGED) {
        const float* __restrict__ Wg = W2 + ((size_t)o * NI + i0) * 64;
        const float* __restrict__ xg = xT + (size_t)i0 * 64;

        // 20 W-chunks + 20 X-chunks of 64 floats (256B) per tile; each wave
        // stages exactly 5+5 = 10 -> uniform vmcnt accounting.
        auto STAGE = [&](int bufn, int tt) {
            const float* ws = Wg + (size_t)tt * TR * 64;
            const float* xs = xg + (size_t)tt * TR * 64;
            float* wl = &Wl[bufn * (TR * 64)];
            float* xl = &Xl[bufn * (TR * 64)];
            #pragma unroll
            for (int c = 0; c < 5; ++c) {
                const int cc = c * 4 + wave;
                gload4(ws + cc * 64 + lane, wl + cc * 64);
                gload4(xs + cc * 64 + lane, xl + cc * 64);
            }
        };

        auto COMPUTE = [&](int bufn) {
            const float* wl = &Wl[bufn * (TR * 64)];
            const float* xl = &Xl[bufn * (TR * 64)];
            #pragma unroll
            for (int r = 0; r < TR; ++r) {
                const float4 w = *(const float4*)(wl + r * 64 + 4 * kg);
                const float4 x = *(const float4*)(xl + r * 64 + b0);
                fma16(w, x);
            }
        };

        STAGE(0, 0);
        STAGE(1, 1);
        int buf = 0;
        for (int t = 0; t < NT - 1; ++t) {
            // tile t's 10 loads are the oldest; allow tile t+1's 10 in flight
            asm volatile("s_waitcnt vmcnt(10)" ::: "memory");
            __builtin_amdgcn_s_barrier();
            if (t + 2 < NT) {
                int nb = buf + 2; if (nb >= 3) nb -= 3;
                STAGE(nb, t + 2);
            }
            COMPUTE(buf);
            buf = (buf == 2) ? 0 : buf + 1;
        }
        asm volatile("s_waitcnt vmcnt(0)" ::: "memory");
        __builtin_amdgcn_s_barrier();
        COMPUTE(buf);
    } else {
        // tiny-NI path (CH == 10): full unroll, all loads issue up front
        const float4* __restrict__ wq = (const float4*)(W2 + ((size_t)o * NI + i0) * 64) + kg;
        const float4* __restrict__ xq = (const float4*)(xT + (size_t)i0 * 64) + (wave * 4 + bgl);
        #pragma unroll
        for (int i = 0; i < CH; ++i) fma16(wq[i * 16], xq[i * 16]);
    }

    // bias-dot: xb[a] = sum over this block's i of x[b0+a, i] * b2[o*NI+i],
    // i interleaved across the 16 k-groups; reduced by the epilogue butterfly.
    const float* __restrict__ b2w = b2 + (size_t)o * NI;
    float xb[4] = {0.f, 0.f, 0.f, 0.f};
    constexpr int T16 = (CH + 15) / 16;
    #pragma unroll 4
    for (int t = 0; t < T16; ++t) {
        const int ib = i0 + t * 16 + kg;
        if (ib < iend) {
            const float  bv = b2w[ib];
            const float4 xv = *(const float4*)(xT + (size_t)ib * 64 + b0);
            xb[0] = fmaf(xv.x, bv, xb[0]);
            xb[1] = fmaf(xv.y, bv, xb[1]);
            xb[2] = fmaf(xv.z, bv, xb[2]);
            xb[3] = fmaf(xv.w, bv, xb[3]);
        }
    }

    // epilogue: contract with h over k, fold in hyper bias row (s==0 only)
    float4 wb = make_float4(0.f, 0.f, 0.f, 0.f);
    if (!ATOMIC || s == 0)
        wb = *(const float4*)(W2 + ((size_t)NO * NI + o) * 64 + 4 * kg);

    float out0, out1, out2, out3;
    #pragma unroll
    for (int a = 0; a < 4; ++a) {
        const float4 hv = *(const float4*)(h + (size_t)(b0 + a) * 64 + 4 * kg);
        float v = xb[a];
        v = fmaf(hv.x, acc[a][0] + wb.x, v);
        v = fmaf(hv.y, acc[a][1] + wb.y, v);
        v = fmaf(hv.z, acc[a][2] + wb.z, v);
        v = fmaf(hv.w, acc[a][3] + wb.w, v);
        // reduce over the 16 k-group lanes (bits 0..3 of lane)
        v += __shfl_xor(v, 1, 64);
        v += __shfl_xor(v, 2, 64);
        v += __shfl_xor(v, 4, 64);
        v += __shfl_xor(v, 8, 64);
        if (a == 0) out0 = v;
        else if (a == 1) out1 = v;
        else if (a == 2) out2 = v;
        else out3 = v;
    }

    if (kg < 4) {
        // lane kg writes b = b0 + kg  (branchless static select, no scratch)
        float v = out0;
        v = (kg == 1) ? out1 : v;
        v = (kg == 2) ? out2 : v;
        v = (kg == 3) ? out3 : v;
        const int b = b0 + kg;
        if (!ATOMIC || s == 0) v += b2[(size_t)NO * NI + o];
        if (TANH) v = tanhf(v);
        if (ATOMIC) atomicAdd(&yT[o * 64 + b], v);
        else        yT[o * 64 + b] = v;
    }
}

// ---------------------------------------------------------------------------
// finalize: d_out = [ z_reconst (64x2000 b-major) , x_enc (64x10 b-major) ]
// ---------------------------------------------------------------------------
__global__ __launch_bounds__(256) void final_kernel(
    const float* __restrict__ d3,   // 2000 x 64 (o-major)
    const float* __restrict__ y3,   // 10 x 64 (o-major)
    float* __restrict__ out)
{
    int t = blockIdx.x * 256 + threadIdx.x;
    if (t < 128000) {
        int b = t / 2000, oo = t - b * 2000;
        out[t] = d3[oo * 64 + b];
    } else if (t < 128640) {
        int u = t - 128000;
        int b = u / 10, oo = u - b * 10;
        out[t] = y3[oo * 64 + b];
    }
}

extern "C" void kernel_launch(void* const* d_in, const int* in_sizes, int n_in,
                              void* d_out, int out_size, void* d_ws, size_t ws_size,
                              hipStream_t stream)
{
    const float* z    = (const float*)d_in[0];
    const float* mu   = (const float*)d_in[1];
    const float* enW0 = (const float*)d_in[2];
    const float* enb0 = (const float*)d_in[3];
    const float* enW1 = (const float*)d_in[4];
    const float* enb1 = (const float*)d_in[5];
    const float* enW2 = (const float*)d_in[6];
    const float* enb2 = (const float*)d_in[7];
    const float* deW0 = (const float*)d_in[8];
    const float* deb0 = (const float*)d_in[9];
    const float* deW1 = (const float*)d_in[10];
    const float* deb1 = (const float*)d_in[11];
    const float* deW2 = (const float*)d_in[12];
    const float* deb2 = (const float*)d_in[13];

    float* ws  = (float*)d_ws;
    float* zT  = ws;                 // 2000*64
    float* hen = zT + 128000;        // 64*64
    float* hde = hen + 4096;         // 64*64
    float* y1  = hde + 4096;         // 200*64  (atomic target -> zeroed)
    float* y2  = y1 + 200 * 64;      // 100*64
    float* y3  = y2 + 100 * 64;      // 10*64   (x_enc, transposed; atomic -> zeroed)
    float* d1  = y3 + 10 * 64;       // 100*64
    float* d2  = d1 + 100 * 64;      // 200*64
    float* d3  = d2 + 200 * 64;      // 2000*64
    float* out = (float*)d_out;

    hipMemsetAsync(y1, 0, 200 * 64 * sizeof(float), stream);
    hipMemsetAsync(y3, 0, 10 * 64 * sizeof(float), stream);
    prep_kernel<<<64, 256, 0, stream>>>(z, mu, enW0, enb0, enW1, enb1,
                                        deW0, deb0, deW1, deb1, zT, hen, hde);
    // encoder  (tanh layers must be NSPLIT=1: tanh of partial sums is wrong)
    fc_kernel<2000, 200, 10, false, true ><<<2000, 256, 0, stream>>>(zT, hen, enW2, enb2, y1);
    fc_kernel< 200, 100,  1, true,  false><<< 100, 256, 0, stream>>>(y1, hen, enW2 + (size_t)400200 * 64, enb2 + 400200, y2);
    fc_kernel< 100,  10, 10, false, true ><<< 100, 256, 0, stream>>>(y2, hen, enW2 + (size_t)420300 * 64, enb2 + 420300, y3);
    // decoder
    fc_kernel<  10, 100,  1, false, false><<< 100, 256, 0, stream>>>(y3, hde, deW2, deb2, d1);
    fc_kernel< 100, 200,  1, true,  false><<< 200, 256, 0, stream>>>(d1, hde, deW2 + (size_t)1100 * 64, deb2 + 1100, d2);
    fc_kernel< 200, 2000, 1, false, false><<<2000, 256, 0, stream>>>(d2, hde, deW2 + (size_t)21300 * 64, deb2 + 21300, d3);

    final_kernel<<<(128640 + 255) / 256, 256, 0, stream>>>(d3, y3, out);
}

// Round 6
// 537.763 us; speedup vs baseline: 1.0390x; 1.0390x over previous
//
#include <hip/hip_runtime.h>
#include <stdint.h>

// SparseAutoEncoder: hypernetwork-generated per-sample MLP weights, fused.
// EN layers (rows in en_W2): (2000,200) lin @0, (200,100) tanh @400200, (100,10) lin @420300
// DE layers (rows in de_W2): (10,100) lin @0, (100,200) tanh @1100, (200,2000) lin @21300
// All hyper widths K = 64, batch B = 64. h layout: (b,k) b-major. xT layouts: (i,b) i-major.

// ---------------------------------------------------------------------------
// prep: transpose z (64x2000) -> zT (2000x64), and compute h_en, h_de (64x64)
// ---------------------------------------------------------------------------
__global__ __launch_bounds__(256) void prep_kernel(
    const float* __restrict__ z, const float* __restrict__ mu,
    const float* __restrict__ enW0, const float* __restrict__ enb0,
    const float* __restrict__ enW1, const float* __restrict__ enb1,
    const float* __restrict__ deW0, const float* __restrict__ deb0,
    const float* __restrict__ deW1, const float* __restrict__ deb1,
    float* __restrict__ zT, float* __restrict__ hen, float* __restrict__ hde)
{
    __shared__ float tile[64 * 65];
    __shared__ float h0s[4][64];
    const int bid  = blockIdx.x;
    const int lane = threadIdx.x & 63;
    const int g    = threadIdx.x >> 6;

    if (bid < 32) {
        // 64x64 tile transpose of z
        const int t0 = bid * 64;
        for (int bb = g; bb < 64; bb += 4) {
            int i = t0 + lane;
            tile[bb * 65 + lane] = (i < 2000) ? z[bb * 2000 + i] : 0.f;
        }
        __syncthreads();
        for (int ii = g; ii < 64; ii += 4) {
            int i = t0 + ii;
            if (i < 2000) zT[i * 64 + lane] = tile[lane * 65 + ii];
        }
    } else {
        // hypernetwork MLP: task = (which, b); lane = output neuron j
        const int task  = (bid - 32) * 4 + g;   // 0..127
        const int which = task >> 6;            // 0 = en, 1 = de
        const int b     = task & 63;
        const float* W0 = which ? deW0 : enW0;
        const float* b0 = which ? deb0 : enb0;
        const float* W1 = which ? deW1 : enW1;
        const float* b1 = which ? deb1 : enb1;
        float* hout     = which ? hde : hen;
        const int j = lane;
        float m0 = mu[b * 4 + 0], m1 = mu[b * 4 + 1], m2 = mu[b * 4 + 2], m3 = mu[b * 4 + 3];
        float v = tanhf(m0 * W0[j * 4 + 0] + m1 * W0[j * 4 + 1] +
                        m2 * W0[j * 4 + 2] + m3 * W0[j * 4 + 3] + b0[j]);
        h0s[g][j] = v;
        __syncthreads();
        float a = b1[j];
        const float* W1r = W1 + j * 64;
        #pragma unroll 8
        for (int k = 0; k < 64; ++k) a = fmaf(h0s[g][k], W1r[k], a);
        hout[b * 64 + j] = tanhf(a);
    }
}

// ---------------------------------------------------------------------------
// async global -> LDS, 16 bytes per lane. Global src is per-lane; LDS dest is
// wave-uniform base + lane*16 (hardware-linear; our LDS layout is linear).
// ---------------------------------------------------------------------------
__device__ __forceinline__ void gload16(const float* g, float* l)
{
    __builtin_amdgcn_global_load_lds(
        (const __attribute__((address_space(1))) void*)g,
        (__attribute__((address_space(3))) void*)l,
        16, 0, 0);
}

// ---------------------------------------------------------------------------
// fc_kernel (R4, unchanged): 4x4 outer-product, 2-phase global_load_lds
// double-buffer. Used for the 4 middle/small layers (latency-bound, small
// grids) where it measured well. Per row: 2 ds_read_b128 + 16 FMAs.
// NOTE: TANH layers must NOT be atomic-split (tanh of partial sums is wrong).
// ---------------------------------------------------------------------------
template <int NI, int NO, int NSPLIT, bool TANH, bool ATOMIC>
__global__ __launch_bounds__(256, 8) void fc_kernel(
    const float* __restrict__ xT,   // NI x 64
    const float* __restrict__ h,    // 64 x 64 (b-major)
    const float* __restrict__ W2,   // layer base, (NO*NI+NO) x 64
    const float* __restrict__ b2,   // layer base, NO*NI+NO
    float* __restrict__ yT)         // NO x 64
{
    const int lane = threadIdx.x & 63;
    const int wave = threadIdx.x >> 6;
    const int kg   = lane & 15;          // k = 4*kg .. 4*kg+3
    const int bgl  = lane >> 4;          // 0..3
    const int b0   = wave * 16 + bgl * 4;

    const int o = blockIdx.x % NO;
    const int s = blockIdx.x / NO;
    constexpr int CH = NI / NSPLIT;      // NI divisible by NSPLIT
    const int i0   = s * CH;
    const int iend = i0 + CH;

    constexpr int  TR     = 20;                          // rows per tile (5 KB per array)
    constexpr bool STAGED = (CH >= TR) && (CH % TR == 0);
    constexpr int  NT     = STAGED ? (CH / TR) : 1;
    constexpr int  CHUNKS = TR / 4;                      // 1KB global_load_lds chunks per tile

    __shared__ float Wl[STAGED ? 2 * TR * 64 : 4];
    __shared__ float Xl[STAGED ? 2 * TR * 64 : 4];

    float acc[4][4];
    #pragma unroll
    for (int a = 0; a < 4; ++a)
        #pragma unroll
        for (int c = 0; c < 4; ++c) acc[a][c] = 0.f;

    auto fma16 = [&](const float4& w, const float4& x) {
        acc[0][0] = fmaf(x.x, w.x, acc[0][0]);
        acc[0][1] = fmaf(x.x, w.y, acc[0][1]);
        acc[0][2] = fmaf(x.x, w.z, acc[0][2]);
        acc[0][3] = fmaf(x.x, w.w, acc[0][3]);
        acc[1][0] = fmaf(x.y, w.x, acc[1][0]);
        acc[1][1] = fmaf(x.y, w.y, acc[1][1]);
        acc[1][2] = fmaf(x.y, w.z, acc[1][2]);
        acc[1][3] = fmaf(x.y, w.w, acc[1][3]);
        acc[2][0] = fmaf(x.z, w.x, acc[2][0]);
        acc[2][1] = fmaf(x.z, w.y, acc[2][1]);
        acc[2][2] = fmaf(x.z, w.z, acc[2][2]);
        acc[2][3] = fmaf(x.z, w.w, acc[2][3]);
        acc[3][0] = fmaf(x.w, w.x, acc[3][0]);
        acc[3][1] = fmaf(x.w, w.y, acc[3][1]);
        acc[3][2] = fmaf(x.w, w.z, acc[3][2]);
        acc[3][3] = fmaf(x.w, w.w, acc[3][3]);
    };

    if constexpr (STAGED) {
        const float* __restrict__ Wg = W2 + ((size_t)o * NI + i0) * 64;
        const float* __restrict__ xg = xT + (size_t)i0 * 64;

        auto STAGE = [&](int bufn, int tt) {
            const float* ws = Wg + (size_t)tt * TR * 64;
            const float* xs = xg + (size_t)tt * TR * 64;
            float* wl = &Wl[bufn * (TR * 64)];
            float* xl = &Xl[bufn * (TR * 64)];
            for (int c = wave; c < CHUNKS; c += 4) {   // 1KB per instr: 64 lanes x 16B
                gload16(ws + c * 256 + lane * 4, wl + c * 256);
                gload16(xs + c * 256 + lane * 4, xl + c * 256);
            }
        };

        STAGE(0, 0);
        __syncthreads();                 // drains vmcnt(0) before consuming buf 0

        int buf = 0;
        for (int t = 0; t < NT; ++t) {
            if (t + 1 < NT) STAGE(buf ^ 1, t + 1);   // flies during this tile's compute
            const float* wl = &Wl[buf * (TR * 64)];
            const float* xl = &Xl[buf * (TR * 64)];
            #pragma unroll
            for (int r = 0; r < TR; ++r) {
                const float4 w = *(const float4*)(wl + r * 64 + 4 * kg);
                const float4 x = *(const float4*)(xl + r * 64 + b0);
                fma16(w, x);
            }
            __syncthreads();             // implicit vmcnt(0): next buffer landed
            buf ^= 1;
        }
    } else {
        // tiny-NI path (CH == 10): full unroll, all loads issue up front
        const float4* __restrict__ wq = (const float4*)(W2 + ((size_t)o * NI + i0) * 64) + kg;
        const float4* __restrict__ xq = (const float4*)(xT + (size_t)i0 * 64) + (wave * 4 + bgl);
        #pragma unroll
        for (int i = 0; i < CH; ++i) fma16(wq[i * 16], xq[i * 16]);
    }

    // bias-dot: xb[a] = sum over this block's i of x[b0+a, i] * b2[o*NI+i]
    const float* __restrict__ b2w = b2 + (size_t)o * NI;
    float xb[4] = {0.f, 0.f, 0.f, 0.f};
    constexpr int T16 = (CH + 15) / 16;
    #pragma unroll 4
    for (int t = 0; t < T16; ++t) {
        const int ib = i0 + t * 16 + kg;
        if (ib < iend) {
            const float  bv = b2w[ib];
            const float4 xv = *(const float4*)(xT + (size_t)ib * 64 + b0);
            xb[0] = fmaf(xv.x, bv, xb[0]);
            xb[1] = fmaf(xv.y, bv, xb[1]);
            xb[2] = fmaf(xv.z, bv, xb[2]);
            xb[3] = fmaf(xv.w, bv, xb[3]);
        }
    }

    // epilogue: contract with h over k, fold in hyper bias row (s==0 only)
    float4 wb = make_float4(0.f, 0.f, 0.f, 0.f);
    if (!ATOMIC || s == 0)
        wb = *(const float4*)(W2 + ((size_t)NO * NI + o) * 64 + 4 * kg);

    float out0, out1, out2, out3;
    #pragma unroll
    for (int a = 0; a < 4; ++a) {
        const float4 hv = *(const float4*)(h + (size_t)(b0 + a) * 64 + 4 * kg);
        float v = xb[a];
        v = fmaf(hv.x, acc[a][0] + wb.x, v);
        v = fmaf(hv.y, acc[a][1] + wb.y, v);
        v = fmaf(hv.z, acc[a][2] + wb.z, v);
        v = fmaf(hv.w, acc[a][3] + wb.w, v);
        v += __shfl_xor(v, 1, 64);
        v += __shfl_xor(v, 2, 64);
        v += __shfl_xor(v, 4, 64);
        v += __shfl_xor(v, 8, 64);
        if (a == 0) out0 = v;
        else if (a == 1) out1 = v;
        else if (a == 2) out2 = v;
        else out3 = v;
    }

    if (kg < 4) {
        float v = out0;
        v = (kg == 1) ? out1 : v;
        v = (kg == 2) ? out2 : v;
        v = (kg == 3) ? out3 : v;
        const int b = b0 + kg;
        if (!ATOMIC || s == 0) v += b2[(size_t)NO * NI + o];
        if (TANH) v = tanhf(v);
        if (ATOMIC) atomicAdd(&yT[o * 64 + b], v);
        else        yT[o * 64 + b] = v;
    }
}

// ---------------------------------------------------------------------------
// fc8_kernel (new): 8k x 8b microkernel for the two BIG layers.
// Lane = (kg = lane&7 -> k-octet, bgl = lane>>3 -> b-octet): ONE wave covers
// the full 64x64 (k,b) tile; block = 4 o's, one per wave -> no cross-wave
// reduction. Per row: 4 ds_read_b128 + 64 FMAs (vs R4's 2 + 16): halves the
// LDS-return-bus traffic per FMA, which R4's counters show is the binding
// resource (2 reads x 12cy x 4 waves = 62us model == 63.6us measured).
// Staging: R4-proven 2-phase global_load_lds + __syncthreads (no asm).
// ---------------------------------------------------------------------------
template <int NI, int NO, int NSPLIT, bool TANH, bool ATOMIC>
__global__ __launch_bounds__(256, 3) void fc8_kernel(
    const float* __restrict__ xT,   // NI x 64
    const float* __restrict__ h,    // 64 x 64 (b-major)
    const float* __restrict__ W2,   // layer base, (NO*NI+NO) x 64
    const float* __restrict__ b2,   // layer base, NO*NI+NO
    float* __restrict__ yT)         // NO x 64
{
    const int lane = threadIdx.x & 63;
    const int wave = threadIdx.x >> 6;
    const int kg   = lane & 7;           // k-octet: k = kg*8 .. kg*8+7
    const int bgl  = lane >> 3;          // b-octet: b = bgl*8 .. bgl*8+7

    constexpr int OQ = NO / 4;           // o-quads (NO divisible by 4)
    const int oq = blockIdx.x % OQ;
    const int s  = blockIdx.x / OQ;
    const int o  = oq * 4 + wave;        // this wave's output neuron
    constexpr int CH = NI / NSPLIT;
    const int i0 = s * CH;

    constexpr int TR = 20;               // rows per tile
    constexpr int NT = CH / TR;          // CH divisible by TR (200 or 100)

    __shared__ float Wl[2][4][TR * 64];  // [buf][o_local][row*64+k]  40 KB
    __shared__ float Xl[2][TR * 64];     // [buf][row*64+b]           10 KB

    float acc[8][8];
    #pragma unroll
    for (int kk = 0; kk < 8; ++kk)
        #pragma unroll
        for (int bb = 0; bb < 8; ++bb) acc[kk][bb] = 0.f;

    // STAGE tile tt into buffer bf: 20 W-chunks (o_l, rb) + 5 X-chunks,
    // each chunk = 4 rows = 256 floats = 1KB (64 lanes x 16B).
    auto STAGE = [&](int bf, int tt) {
        const int bi = i0 + tt * TR;
        #pragma unroll
        for (int c = 0; c < 5; ++c) {
            const int cc = c * 4 + wave;          // 0..19, bijection to (ol, rb)
            const int ol = cc / 5, rb = cc % 5;
            gload16(W2 + ((size_t)(oq * 4 + ol) * NI + bi + rb * 4) * 64 + lane * 4,
                    &Wl[bf][ol][rb * 256]);
        }
        for (int c2 = wave; c2 < 5; c2 += 4)
            gload16(xT + (size_t)(bi + c2 * 4) * 64 + lane * 4, &Xl[bf][c2 * 256]);
    };

    auto COMPUTE = [&](int bf) {
        const float* __restrict__ wl = &Wl[bf][wave][0];
        const float* __restrict__ xl = &Xl[bf][0];
        #pragma unroll
        for (int r = 0; r < TR; ++r) {
            const float4 wA = *(const float4*)(wl + r * 64 + kg * 8);
            const float4 wB = *(const float4*)(wl + r * 64 + kg * 8 + 4);
            const float4 xA = *(const float4*)(xl + r * 64 + bgl * 8);
            const float4 xB = *(const float4*)(xl + r * 64 + bgl * 8 + 4);
            const float wv[8] = {wA.x, wA.y, wA.z, wA.w, wB.x, wB.y, wB.z, wB.w};
            const float xv[8] = {xA.x, xA.y, xA.z, xA.w, xB.x, xB.y, xB.z, xB.w};
            #pragma unroll
            for (int kk = 0; kk < 8; ++kk)
                #pragma unroll
                for (int bb = 0; bb < 8; ++bb)
                    acc[kk][bb] = fmaf(xv[bb], wv[kk], acc[kk][bb]);
        }
    };

    STAGE(0, 0);
    __syncthreads();                     // drains vmcnt(0) before consuming buf 0
    int buf = 0;
    for (int t = 0; t < NT; ++t) {
        if (t + 1 < NT) STAGE(buf ^ 1, t + 1);
        COMPUTE(buf);
        __syncthreads();                 // implicit vmcnt(0): next buffer landed
        buf ^= 1;
    }

    // bias-dot: xb[bb] = sum_i x[bgl*8+bb, i] * b2[o*NI+i]; i interleaved over
    // the 8 kg groups; the epilogue's xor-reduce over kg completes the sum.
    const float* __restrict__ b2w = b2 + (size_t)o * NI;
    float xb[8];
    #pragma unroll
    for (int bb = 0; bb < 8; ++bb) xb[bb] = 0.f;
    constexpr int T8 = (CH + 7) / 8;
    #pragma unroll 4
    for (int t = 0; t < T8; ++t) {
        const int ib = i0 + t * 8 + kg;
        if (ib < i0 + CH) {
            const float  bv = b2w[ib];
            const float4 xA = *(const float4*)(xT + (size_t)ib * 64 + bgl * 8);
            const float4 xB = *(const float4*)(xT + (size_t)ib * 64 + bgl * 8 + 4);
            xb[0] = fmaf(xA.x, bv, xb[0]);
            xb[1] = fmaf(xA.y, bv, xb[1]);
            xb[2] = fmaf(xA.z, bv, xb[2]);
            xb[3] = fmaf(xA.w, bv, xb[3]);
            xb[4] = fmaf(xB.x, bv, xb[4]);
            xb[5] = fmaf(xB.y, bv, xb[5]);
            xb[6] = fmaf(xB.z, bv, xb[6]);
            xb[7] = fmaf(xB.w, bv, xb[7]);
        }
    }

    // hyper bias row for this o (only s==0 when atomic-split)
    float wbv[8] = {0.f, 0.f, 0.f, 0.f, 0.f, 0.f, 0.f, 0.f};
    if (!ATOMIC || s == 0) {
        const float4 wbA = *(const float4*)(W2 + ((size_t)NO * NI + o) * 64 + kg * 8);
        const float4 wbB = *(const float4*)(W2 + ((size_t)NO * NI + o) * 64 + kg * 8 + 4);
        wbv[0] = wbA.x; wbv[1] = wbA.y; wbv[2] = wbA.z; wbv[3] = wbA.w;
        wbv[4] = wbB.x; wbv[5] = wbB.y; wbv[6] = wbB.z; wbv[7] = wbB.w;
    }

    // epilogue: v_bb = xb[bb] + sum_kk h[b,kg*8+kk]*(acc[kk][bb]+wbv[kk]);
    // xor-reduce over lane bits 0..2 (the kg octet) completes both sums.
    float myv = 0.f;
    #pragma unroll
    for (int bb = 0; bb < 8; ++bb) {
        const int b = bgl * 8 + bb;
        const float4 hA = *(const float4*)(h + (size_t)b * 64 + kg * 8);
        const float4 hB = *(const float4*)(h + (size_t)b * 64 + kg * 8 + 4);
        const float hv[8] = {hA.x, hA.y, hA.z, hA.w, hB.x, hB.y, hB.z, hB.w};
        float v = xb[bb];
        #pragma unroll
        for (int kk = 0; kk < 8; ++kk)
            v = fmaf(hv[kk], acc[kk][bb] + wbv[kk], v);
        v += __shfl_xor(v, 1, 64);
        v += __shfl_xor(v, 2, 64);
        v += __shfl_xor(v, 4, 64);
        if (kg == bb) myv = v;
    }

    const int b = bgl * 8 + kg;          // every lane writes exactly one output
    float outv = myv;
    if (!ATOMIC || s == 0) outv += b2[(size_t)NO * NI + o];
    if (TANH) outv = tanhf(outv);
    if (ATOMIC) atomicAdd(&yT[o * 64 + b], outv);
    else        yT[o * 64 + b] = outv;
}

// ---------------------------------------------------------------------------
// finalize: d_out = [ z_reconst (64x2000 b-major) , x_enc (64x10 b-major) ]
// ---------------------------------------------------------------------------
__global__ __launch_bounds__(256) void final_kernel(
    const float* __restrict__ d3,   // 2000 x 64 (o-major)
    const float* __restrict__ y3,   // 10 x 64 (o-major)
    float* __restrict__ out)
{
    int t = blockIdx.x * 256 + threadIdx.x;
    if (t < 128000) {
        int b = t / 2000, oo = t - b * 2000;
        out[t] = d3[oo * 64 + b];
    } else if (t < 128640) {
        int u = t - 128000;
        int b = u / 10, oo = u - b * 10;
        out[t] = y3[oo * 64 + b];
    }
}

extern "C" void kernel_launch(void* const* d_in, const int* in_sizes, int n_in,
                              void* d_out, int out_size, void* d_ws, size_t ws_size,
                              hipStream_t stream)
{
    const float* z    = (const float*)d_in[0];
    const float* mu   = (const float*)d_in[1];
    const float* enW0 = (const float*)d_in[2];
    const float* enb0 = (const float*)d_in[3];
    const float* enW1 = (const float*)d_in[4];
    const float* enb1 = (const float*)d_in[5];
    const float* enW2 = (const float*)d_in[6];
    const float* enb2 = (const float*)d_in[7];
    const float* deW0 = (const float*)d_in[8];
    const float* deb0 = (const float*)d_in[9];
    const float* deW1 = (const float*)d_in[10];
    const float* deb1 = (const float*)d_in[11];
    const float* deW2 = (const float*)d_in[12];
    const float* deb2 = (const float*)d_in[13];

    float* ws  = (float*)d_ws;
    float* zT  = ws;                 // 2000*64
    float* hen = zT + 128000;        // 64*64
    float* hde = hen + 4096;         // 64*64
    float* y1  = hde + 4096;         // 200*64  (atomic target -> zeroed)
    float* y2  = y1 + 200 * 64;      // 100*64
    float* y3  = y2 + 100 * 64;      // 10*64   (x_enc, transposed; atomic -> zeroed)
    float* d1  = y3 + 10 * 64;       // 100*64
    float* d2  = d1 + 100 * 64;      // 200*64
    float* d3  = d2 + 200 * 64;      // 2000*64
    float* out = (float*)d_out;

    hipMemsetAsync(y1, 0, 200 * 64 * sizeof(float), stream);
    hipMemsetAsync(y3, 0, 10 * 64 * sizeof(float), stream);
    prep_kernel<<<64, 256, 0, stream>>>(z, mu, enW0, enb0, enW1, enb1,
                                        deW0, deb0, deW1, deb1, zT, hen, hde);
    // encoder  (tanh layers must be NSPLIT=1: tanh of partial sums is wrong)
    fc8_kernel<2000, 200, 10, false, true ><<<(200/4) * 10, 256, 0, stream>>>(zT, hen, enW2, enb2, y1);
    fc_kernel < 200, 100,  1, true,  false><<< 100, 256, 0, stream>>>(y1, hen, enW2 + (size_t)400200 * 64, enb2 + 400200, y2);
    fc_kernel < 100,  10, 10, false, true ><<< 100, 256, 0, stream>>>(y2, hen, enW2 + (size_t)420300 * 64, enb2 + 420300, y3);
    // decoder
    fc_kernel <  10, 100,  1, false, false><<< 100, 256, 0, stream>>>(y3, hde, deW2, deb2, d1);
    fc_kernel < 100, 200,  1, true,  false><<< 200, 256, 0, stream>>>(d1, hde, deW2 + (size_t)1100 * 64, deb2 + 1100, d2);
    fc8_kernel< 200, 2000, 1, false, false><<<2000/4, 256, 0, stream>>>(d2, hde, deW2 + (size_t)21300 * 64, deb2 + 21300, d3);

    final_kernel<<<(128640 + 255) / 256, 256, 0, stream>>>(d3, y3, out);
}